// Round 9
// baseline (706.781 us; speedup 1.0000x reference)
//
#include <hip/hip_runtime.h>
#include <hip/hip_bf16.h>
#include <stdint.h>

// out[n, m=c*64+i, r] = sum_j (S*W[c,r,i,j]) * X[n,r,j],  S = DELTA_G*DELTA_V
// N=4096, M=1024 (c=16 x i=64), R=16, K=64.  GMIN terms cancel exactly.
//
// Round-9: r-in-lane remap kills the LDS output transpose.
//  - wave (a,rg): 16m x 16n x 4r; per r one MFMA pair (K=64 -> 2x 16x16x32).
//  - lane (lr,lk), reg: {acc_r0..r3}[reg] = out[n0+lr][m][rg*4..+3] -> one
//    f32x4 nt store. The 4 rg-waves complete each 64B r-row within the same
//    iter -> L2 merges partials. No ep1/ep2, no O-LDS, ONE barrier/iter.
//  - LDS = X double buffer only, pitch 514 dwords (mod 32 = 2): B-frag
//    ds_read_b128 banks 2*lr all-distinct; stage writes 2-way (free).
//  - keeps: reg prefetch of next X tile, v_cvt_pk via __float22bfloat162_rn,
//    S folded into W at hoist, light barrier, XCD map, nt stores.

using bf16x8 = __attribute__((ext_vector_type(8))) short;
using f32x4  = __attribute__((ext_vector_type(4))) float;

#define NPT 16                 // n per iteration tile
#define NIT 16                 // iterations per block (256 n per block)
#define PITCH_B 2056           // bytes per n-row: 514 dwords (514 mod 32 = 2)
#define BUFB (16 * PITCH_B)    // 32896
#define LDS_BYTES (2 * BUFB)   // 65792 -> 2 blocks/CU

// LDS-only barrier: order ds ops across waves without draining the VM queue.
#define BARRIER() asm volatile("s_waitcnt lgkmcnt(0)\n\ts_barrier" ::: "memory")

__device__ inline bf16x8 cvt8v(float4 a, float4 b) {
  union { bf16x8 v; __hip_bfloat162 h[4]; } r;
  r.h[0] = __float22bfloat162_rn(float2{a.x, a.y});
  r.h[1] = __float22bfloat162_rn(float2{a.z, a.w});
  r.h[2] = __float22bfloat162_rn(float2{b.x, b.y});
  r.h[3] = __float22bfloat162_rn(float2{b.z, b.w});
  return r.v;
}

__global__ __launch_bounds__(512, 4)
void crxb_kernel(const float* __restrict__ X, const float* __restrict__ W,
                 float* __restrict__ out) {
  extern __shared__ char smem[];
  const int t   = threadIdx.x;
  const int bid = blockIdx.x;
  // XCD-aware mapping: each XCD owns 2 n-groups; all 32 m-tiles of a given
  // n-group land on the same XCD -> X slice stays in that XCD's L2.
  const int ngrp = ((bid & 7) << 1) | ((bid >> 3) & 1);  // 0..15, 256 n each
  const int mt   = bid >> 4;                             // 0..31
  const int c  = mt >> 1;
  const int i0 = (mt & 1) << 5;
  const int m0 = mt << 5;

  const int wid = t >> 6;
  const int l   = t & 63;
  const int lr  = l & 15;            // A row (m within 16) / B col (n)
  const int lk  = l >> 4;            // k-subgroup 0..3
  const int a   = wid & 1;           // m-half (0: m0..m0+15, 1: m0+16..m0+31)
  const int rg  = wid >> 1;          // r-quarter: r = rg*4 .. rg*4+3

  const float S = (float)((0.000333 - 3.33e-07) * (3.3 / 255.0));

  // ---- hoist A fragments: (S*W) fp32 global -> bf16 regs (once per block) ----
  bf16x8 A[4][2];                    // [rr][ks]
  #pragma unroll
  for (int rr = 0; rr < 4; ++rr)
    #pragma unroll
    for (int ks = 0; ks < 2; ++ks) {
      const float* gw = W + (((size_t)(c * 16 + rg * 4 + rr) * 64) + (i0 + a * 16 + lr)) * 64
                          + ks * 32 + lk * 8;
      float4 wa = *(const float4*)gw;
      float4 wb = *(const float4*)(gw + 4);
      wa.x *= S; wa.y *= S; wa.z *= S; wa.w *= S;
      wb.x *= S; wb.y *= S; wb.z *= S; wb.w *= S;
      A[rr][ks] = cvt8v(wa, wb);
    }

  // ---- prologue: stage X tile 0 into buf0 ----
  {
    #pragma unroll
    for (int p = 0; p < 4; ++p) {
      int u = p * 512 + t;                     // 0..2047 bf16x8 units
      int n = u >> 7, r = (u >> 3) & 15, k8 = u & 7;
      const float* gx = X + (((size_t)(ngrp * 256 + n) * 16) + r) * 64 + k8 * 8;
      *(bf16x8*)(smem + (size_t)n * PITCH_B + r * 128 + k8 * 16) =
          cvt8v(*(const float4*)gx, *(const float4*)(gx + 4));
    }
  }
  BARRIER();

  int cur = 0;
  for (int it = 0; it < NIT; ++it) {
    char* bufc = smem + cur * BUFB;
    char* bufn = smem + (cur ^ 1) * BUFB;
    const int n0 = ngrp * 256 + it * NPT;

    // ---- issue next-tile X loads early (latency hides under compute) ----
    float4 xp[8];
    if (it + 1 < NIT) {
      #pragma unroll
      for (int p = 0; p < 4; ++p) {
        int u = p * 512 + t;
        int n = u >> 7, r = (u >> 3) & 15, k8 = u & 7;
        const float* gx = X + (((size_t)(n0 + NPT + n) * 16) + r) * 64 + k8 * 8;
        xp[2 * p]     = *(const float4*)gx;
        xp[2 * p + 1] = *(const float4*)(gx + 4);
      }
    }

    // ---- compute: 16m x 16n x 4r per wave, 8 MFMAs ----
    f32x4 acc[4];                    // [rr]
    #pragma unroll
    for (int rr = 0; rr < 4; ++rr) acc[rr] = (f32x4){0.f, 0.f, 0.f, 0.f};

    #pragma unroll
    for (int rr = 0; rr < 4; ++rr) {
      const int r = rg * 4 + rr;
      #pragma unroll
      for (int ks = 0; ks < 2; ++ks) {
        bf16x8 Bf = *(const bf16x8*)(bufc + (size_t)lr * PITCH_B + r * 128 + ks * 64 + lk * 16);
        acc[rr] = __builtin_amdgcn_mfma_f32_16x16x32_bf16(A[rr][ks], Bf, acc[rr], 0, 0, 0);
      }
    }

    // ---- direct store: lane(reg) holds out[n0+lr][m][rg*4..+3] contiguous ----
    {
      float* gbase = out + (size_t)(n0 + lr) * 16384 + (size_t)(m0 + a * 16 + lk * 4) * 16 + rg * 4;
      #pragma unroll
      for (int reg = 0; reg < 4; ++reg) {
        f32x4 v = {acc[0][reg], acc[1][reg], acc[2][reg], acc[3][reg]};
        __builtin_nontemporal_store(v, (f32x4*)(gbase + reg * 16));
      }
    }

    // ---- stage next tile: cvt prefetched regs -> bufn ----
    if (it + 1 < NIT) {
      #pragma unroll
      for (int p = 0; p < 4; ++p) {
        int u = p * 512 + t;
        int n = u >> 7, r = (u >> 3) & 15, k8 = u & 7;
        *(bf16x8*)(bufn + (size_t)n * PITCH_B + r * 128 + k8 * 16) = cvt8v(xp[2 * p], xp[2 * p + 1]);
      }
    }
    BARRIER();                       // stage visible before next compute
    cur ^= 1;
  }
}

extern "C" void kernel_launch(void* const* d_in, const int* in_sizes, int n_in,
                              void* d_out, int out_size, void* d_ws, size_t ws_size,
                              hipStream_t stream) {
  const float* X = (const float*)d_in[0];   // [4096,1,16,64,1]
  const float* W = (const float*)d_in[1];   // [16,16,64,64]
  float* out = (float*)d_out;               // [4096,1024,16]
  (void)in_sizes; (void)n_in; (void)d_ws; (void)ws_size; (void)out_size;

  (void)hipFuncSetAttribute(reinterpret_cast<const void*>(crxb_kernel),
                            hipFuncAttributeMaxDynamicSharedMemorySize, LDS_BYTES);

  crxb_kernel<<<dim3(512), dim3(512), LDS_BYTES, stream>>>(X, W, out);
}

// Round 10
// 108.041 us; speedup vs baseline: 6.5418x; 6.5418x over previous
//
#include <hip/hip_runtime.h>
#include <hip/hip_bf16.h>
#include <stdint.h>

// out[n, m=c*64+i, r] = sum_j (S*W[c,r,i,j]) * X[n,r,j],  S = DELTA_G*DELTA_V
// N=4096, M=1024 (c=16 x i=64), R=16, K=64.  GMIN terms cancel exactly.
//
// Round-10 = round-8 phase structure (59.5us) with ONE lever: occupancy
// 2 -> 4 blocks/CU.  Single 33KB LDS buffer cycling X[it] -> O[it] -> X[it+1]
// (drops the X double-buffer and the xp register prefetch; +1 barrier/iter).
// Grid 1024 x NIT=8 fills all 4 slots/CU in exactly one dispatch round.
// With 4 blocks round-robining, some block is always in ep2 -> store pipe fed.
// Keeps: LDS output transpose (round 9 proved direct 16B stores -> 3.3x
// WRITE_SIZE), v_cvt_pk bf16, S folded into W hoist, light lgkm-only
// barriers, nt float4 stores, XCD-aware map.

using bf16x8 = __attribute__((ext_vector_type(8))) short;
using f32x4  = __attribute__((ext_vector_type(4))) float;
using f32x2  = __attribute__((ext_vector_type(2))) float;

#define NPT 16                 // n per iteration tile
#define NIT 8                  // iterations per block (128 n per block)
#define PITCH_B 2064           // bytes per n-row (516 dwords)
#define BUFB (16 * PITCH_B)    // 33024
#define LDS_BYTES BUFB         // single buffer -> 4 blocks/CU (32 waves = max)

// LDS-only barrier: order ds ops across waves without draining the VM queue.
#define BARRIER() asm volatile("s_waitcnt lgkmcnt(0)\n\ts_barrier" ::: "memory")

__device__ inline bf16x8 cvt8v(float4 a, float4 b) {
  union { bf16x8 v; __hip_bfloat162 h[4]; } r;
  r.h[0] = __float22bfloat162_rn(float2{a.x, a.y});
  r.h[1] = __float22bfloat162_rn(float2{a.z, a.w});
  r.h[2] = __float22bfloat162_rn(float2{b.x, b.y});
  r.h[3] = __float22bfloat162_rn(float2{b.z, b.w});
  return r.v;
}

__global__ __launch_bounds__(512, 8)
void crxb_kernel(const float* __restrict__ X, const float* __restrict__ W,
                 float* __restrict__ out) {
  extern __shared__ char smem[];
  const int t   = threadIdx.x;
  const int bid = blockIdx.x;
  // 1024 blocks = 32 m-tiles x 32 n-groups (128 n each). XCD-aware: all 32
  // m-blocks of one n-group land on one XCD (bid%8) -> X slice L2-resident.
  const int xcd  = bid & 7;
  const int ng   = xcd * 4 + ((bid >> 3) & 3);  // 0..31
  const int mt   = bid >> 5;                    // 0..31
  const int c  = mt >> 1;
  const int i0 = (mt & 1) << 5;
  const int m0 = mt << 5;

  const int wid = t >> 6;
  const int l   = t & 63;
  const int lr  = l & 15;            // A row (m within 16) / B col (n)
  const int lk  = l >> 4;            // k-subgroup 0..3
  const int r0w = wid << 1;          // wave owns r0w, r0w+1

  const float S = (float)((0.000333 - 3.33e-07) * (3.3 / 255.0));

  // ---- hoist A fragments: (S*W) fp32 global -> bf16 regs (once per block) ----
  bf16x8 A[2][2][2];                 // [rr][ks][a]
  #pragma unroll
  for (int rr = 0; rr < 2; ++rr)
    #pragma unroll
    for (int ks = 0; ks < 2; ++ks)
      #pragma unroll
      for (int a = 0; a < 2; ++a) {
        const float* gw = W + (((size_t)(c * 16 + r0w + rr) * 64) + (i0 + a * 16 + lr)) * 64
                            + ks * 32 + lk * 8;
        float4 wa = *(const float4*)gw;
        float4 wb = *(const float4*)(gw + 4);
        wa.x *= S; wa.y *= S; wa.z *= S; wa.w *= S;
        wb.x *= S; wb.y *= S; wb.z *= S; wb.w *= S;
        A[rr][ks][a] = cvt8v(wa, wb);
      }

  // ---- prologue: stage X tile 0 ----
  {
    #pragma unroll
    for (int p = 0; p < 4; ++p) {
      int u = p * 512 + t;                     // 0..2047 bf16x8 units
      int n = u >> 7, r = (u >> 3) & 15, k8 = u & 7;
      const float* gx = X + (((size_t)(ng * 128 + n) * 16) + r) * 64 + k8 * 8;
      *(bf16x8*)(smem + (size_t)n * PITCH_B + r * 128 + k8 * 16) =
          cvt8v(*(const float4*)gx, *(const float4*)(gx + 4));
    }
  }
  BARRIER();

  for (int it = 0; it < NIT; ++it) {
    const int n0 = ng * 128 + it * NPT;

    // ---- compute: 32m x 16n, 2 r's per wave, 8 MFMAs ----
    f32x4 acc[2][2];                 // [rr][a]
    #pragma unroll
    for (int rr = 0; rr < 2; ++rr)
      #pragma unroll
      for (int a = 0; a < 2; ++a) acc[rr][a] = (f32x4){0.f, 0.f, 0.f, 0.f};

    #pragma unroll
    for (int rr = 0; rr < 2; ++rr) {
      const int r = r0w + rr;
      #pragma unroll
      for (int ks = 0; ks < 2; ++ks) {
        bf16x8 Bf = *(const bf16x8*)(smem + (size_t)lr * PITCH_B + r * 128 + ks * 64 + lk * 16);
        acc[rr][0] = __builtin_amdgcn_mfma_f32_16x16x32_bf16(A[rr][ks][0], Bf, acc[rr][0], 0, 0, 0);
        acc[rr][1] = __builtin_amdgcn_mfma_f32_16x16x32_bf16(A[rr][ks][1], Bf, acc[rr][1], 0, 0, 0);
      }
    }
    BARRIER();                       // X reads done; buffer becomes O

    // ---- ep1: acc -> O (fp32) transpose in LDS; r-paired float2 stores ----
    #pragma unroll
    for (int a = 0; a < 2; ++a)
      #pragma unroll
      for (int reg = 0; reg < 4; ++reg) {
        f32x2 v = {acc[0][a][reg], acc[1][a][reg]};
        const int mm = a * 16 + lk * 4 + reg;     // m within 32
        *(f32x2*)(smem + ((size_t)lr * 516 + mm * 16 + r0w) * 4) = v;
      }
    BARRIER();

    // ---- ep2: O -> global, coalesced NONTEMPORAL float4 stores ----
    {
      const int n  = t >> 5;         // 0..15
      const int j0 = t & 31;
      const float* Or = (const float*)(smem + (size_t)n * PITCH_B);
      float* gout = out + ((size_t)(n0 + n)) * 16384 + (size_t)m0 * 16;
      #pragma unroll
      for (int q = 0; q < 4; ++q) {
        const int u = (q * 32 + j0) * 4;          // dword offset
        f32x4 v = *(const f32x4*)(Or + u);
        __builtin_nontemporal_store(v, (f32x4*)(gout + u));
      }
    }

    // ---- stage next X tile (direct global -> cvt -> LDS) ----
    if (it + 1 < NIT) {
      BARRIER();                     // ep2 reads done; buffer becomes X again
      #pragma unroll
      for (int p = 0; p < 4; ++p) {
        int u = p * 512 + t;
        int n = u >> 7, r = (u >> 3) & 15, k8 = u & 7;
        const float* gx = X + (((size_t)(n0 + NPT + n) * 16) + r) * 64 + k8 * 8;
        *(bf16x8*)(smem + (size_t)n * PITCH_B + r * 128 + k8 * 16) =
            cvt8v(*(const float4*)gx, *(const float4*)(gx + 4));
      }
      BARRIER();                     // stage visible before next compute
    }
  }
}

extern "C" void kernel_launch(void* const* d_in, const int* in_sizes, int n_in,
                              void* d_out, int out_size, void* d_ws, size_t ws_size,
                              hipStream_t stream) {
  const float* X = (const float*)d_in[0];   // [4096,1,16,64,1]
  const float* W = (const float*)d_in[1];   // [16,16,64,64]
  float* out = (float*)d_out;               // [4096,1024,16]
  (void)in_sizes; (void)n_in; (void)d_ws; (void)ws_size; (void)out_size;

  (void)hipFuncSetAttribute(reinterpret_cast<const void*>(crxb_kernel),
                            hipFuncAttributeMaxDynamicSharedMemorySize, LDS_BYTES);

  crxb_kernel<<<dim3(1024), dim3(512), LDS_BYTES, stream>>>(X, W, out);
}

// Round 11
// 97.648 us; speedup vs baseline: 7.2380x; 1.1064x over previous
//
#include <hip/hip_runtime.h>
#include <hip/hip_bf16.h>
#include <stdint.h>

// out[n, m=c*64+i, r] = sum_j (S*W[c,r,i,j]) * X[n,r,j],  S = DELTA_G*DELTA_V
// N=4096, M=1024 (c=16 x i=64), R=16, K=64.  GMIN terms cancel exactly.
//
// Round-11 = round-8 dataflow (59.5us: X dbuf, LDS O-transpose, 3 light
// barriers/iter, nt stores, XCD map) with ONE lever: 1024-thread blocks,
// 16 thin waves, ONE r per wave. Per-wave regs collapse (A 16 + acc 8 +
// xp 16 ~ 60 VGPR) -> launch_bounds(1024,8) targets <=64 VGPR ->
// 32 waves/CU (hardware max) at the same 2 blocks/CU LDS budget.
// Attacks the latency-bound phase chain with 2x TLP + half per-wave work.

using bf16x8 = __attribute__((ext_vector_type(8))) short;
using f32x4  = __attribute__((ext_vector_type(4))) float;

#define NPT 16                 // n per iteration tile
#define NIT 16                 // iterations per block (256 n per block)
#define PITCH_B 2064           // bytes per n-row in LDS (516 dwords)
#define BUFB 33024             // 16 rows * 2064
#define LDS_BYTES (2*BUFB)     // 66048: double buffer -> 2 blocks/CU

// LDS-only barrier: order ds ops across waves without draining the VM queue.
#define BARRIER() asm volatile("s_waitcnt lgkmcnt(0)\n\ts_barrier" ::: "memory")

__device__ inline bf16x8 cvt8v(float4 a, float4 b) {
  union { bf16x8 v; __hip_bfloat162 h[4]; } r;
  r.h[0] = __float22bfloat162_rn(float2{a.x, a.y});
  r.h[1] = __float22bfloat162_rn(float2{a.z, a.w});
  r.h[2] = __float22bfloat162_rn(float2{b.x, b.y});
  r.h[3] = __float22bfloat162_rn(float2{b.z, b.w});
  return r.v;
}

__global__ __launch_bounds__(1024, 8)
void crxb_kernel(const float* __restrict__ X, const float* __restrict__ W,
                 float* __restrict__ out) {
  extern __shared__ char smem[];
  const int t   = threadIdx.x;
  const int bid = blockIdx.x;
  // XCD-aware mapping: each XCD owns 2 n-groups; all 32 m-tiles of a given
  // n-group land on the same XCD -> X slice stays in that XCD's L2.
  const int ngrp = ((bid & 7) << 1) | ((bid >> 3) & 1);  // 0..15, 256 n each
  const int mt   = bid >> 4;                             // 0..31
  const int c  = mt >> 1;
  const int i0 = (mt & 1) << 5;
  const int m0 = mt << 5;

  const int wid = t >> 6;            // 0..15 == the wave's r
  const int l   = t & 63;
  const int lr  = l & 15;            // A row (m within 16) / B col (n)
  const int lk  = l >> 4;            // k-subgroup 0..3

  const float S = (float)((0.000333 - 3.33e-07) * (3.3 / 255.0));

  // ---- hoist A fragments: (S*W) fp32 global -> bf16 regs (once per block) ----
  bf16x8 A[2][2];                    // [ks][a], r = wid
  #pragma unroll
  for (int ks = 0; ks < 2; ++ks)
    #pragma unroll
    for (int a = 0; a < 2; ++a) {
      const float* gw = W + (((size_t)(c * 16 + wid) * 64) + (i0 + a * 16 + lr)) * 64
                          + ks * 32 + lk * 8;
      float4 wa = *(const float4*)gw;
      float4 wb = *(const float4*)(gw + 4);
      wa.x *= S; wa.y *= S; wa.z *= S; wa.w *= S;
      wb.x *= S; wb.y *= S; wb.z *= S; wb.w *= S;
      A[ks][a] = cvt8v(wa, wb);
    }

  // ---- prologue: stage X tile 0 into buf0 ----
  {
    #pragma unroll
    for (int p = 0; p < 2; ++p) {
      int u = p * 1024 + t;                    // 0..2047 bf16x8 units
      int n = u >> 7, r = (u >> 3) & 15, k8 = u & 7;
      const float* gx = X + (((size_t)(ngrp * 256 + n) * 16) + r) * 64 + k8 * 8;
      *(bf16x8*)(smem + (size_t)n * PITCH_B + r * 128 + k8 * 16) =
          cvt8v(*(const float4*)gx, *(const float4*)(gx + 4));
    }
  }
  BARRIER();

  int cur = 0;
  for (int it = 0; it < NIT; ++it) {
    char* bufc = smem + cur * BUFB;
    char* bufn = smem + (cur ^ 1) * BUFB;
    const int n0 = ngrp * 256 + it * NPT;

    // ---- issue next-tile X loads early (latency hides under compute+eps) ----
    float4 xp[4];
    if (it + 1 < NIT) {
      #pragma unroll
      for (int p = 0; p < 2; ++p) {
        int u = p * 1024 + t;
        int n = u >> 7, r = (u >> 3) & 15, k8 = u & 7;
        const float* gx = X + (((size_t)(n0 + NPT + n) * 16) + r) * 64 + k8 * 8;
        xp[2 * p]     = *(const float4*)gx;
        xp[2 * p + 1] = *(const float4*)(gx + 4);
      }
    }

    // ---- compute: 32m x 16n, ONE r per wave, 4 MFMAs ----
    f32x4 acc[2];                    // [a]
    acc[0] = (f32x4){0.f, 0.f, 0.f, 0.f};
    acc[1] = (f32x4){0.f, 0.f, 0.f, 0.f};

    #pragma unroll
    for (int ks = 0; ks < 2; ++ks) {
      bf16x8 Bf = *(const bf16x8*)(bufc + (size_t)lr * PITCH_B + wid * 128 + ks * 64 + lk * 16);
      acc[0] = __builtin_amdgcn_mfma_f32_16x16x32_bf16(A[ks][0], Bf, acc[0], 0, 0, 0);
      acc[1] = __builtin_amdgcn_mfma_f32_16x16x32_bf16(A[ks][1], Bf, acc[1], 0, 0, 0);
    }
    BARRIER();                       // all reads of bufc done (LDS order only)

    // ---- ep1: acc -> O (fp32) transpose in bufc; scalar dword stores ----
    #pragma unroll
    for (int a = 0; a < 2; ++a)
      #pragma unroll
      for (int reg = 0; reg < 4; ++reg) {
        const int mm = a * 16 + lk * 4 + reg;     // m within 32
        *(float*)(bufc + ((size_t)lr * 516 + mm * 16 + wid) * 4) = acc[a][reg];
      }
    BARRIER();

    // ---- ep2: O -> global; wave w stores row n=w, 1KB contiguous per instr ----
    {
      const int n  = wid;            // row per wave
      const int j0 = l;              // 0..63
      const float* Or = (const float*)(bufc + (size_t)n * PITCH_B);
      float* gout = out + ((size_t)(n0 + n)) * 16384 + (size_t)m0 * 16;
      #pragma unroll
      for (int q = 0; q < 2; ++q) {
        const int u = (q * 64 + j0) * 4;          // dword offset 0..508
        f32x4 v = *(const f32x4*)(Or + u);
        __builtin_nontemporal_store(v, (f32x4*)(gout + u));
      }
    }

    // ---- stage next tile: cvt prefetched regs -> bufn ----
    if (it + 1 < NIT) {
      #pragma unroll
      for (int p = 0; p < 2; ++p) {
        int u = p * 1024 + t;
        int n = u >> 7, r = (u >> 3) & 15, k8 = u & 7;
        *(bf16x8*)(bufn + (size_t)n * PITCH_B + r * 128 + k8 * 16) = cvt8v(xp[2 * p], xp[2 * p + 1]);
      }
    }
    BARRIER();
    cur ^= 1;
  }
}

extern "C" void kernel_launch(void* const* d_in, const int* in_sizes, int n_in,
                              void* d_out, int out_size, void* d_ws, size_t ws_size,
                              hipStream_t stream) {
  const float* X = (const float*)d_in[0];   // [4096,1,16,64,1]
  const float* W = (const float*)d_in[1];   // [16,16,64,64]
  float* out = (float*)d_out;               // [4096,1024,16]
  (void)in_sizes; (void)n_in; (void)d_ws; (void)ws_size; (void)out_size;

  (void)hipFuncSetAttribute(reinterpret_cast<const void*>(crxb_kernel),
                            hipFuncAttributeMaxDynamicSharedMemorySize, LDS_BYTES);

  crxb_kernel<<<dim3(512), dim3(1024), LDS_BYTES, stream>>>(X, W, out);
}

// Round 12
// 76.867 us; speedup vs baseline: 9.1948x; 1.2704x over previous
//
#include <hip/hip_runtime.h>
#include <hip/hip_bf16.h>
#include <stdint.h>

// out[n, m=c*64+i, r] = sum_j (S*W[c,r,i,j]) * X[n,r,j],  S = DELTA_G*DELTA_V
// N=4096, M=1024 (c=16 x i=64), R=16, K=64.  GMIN terms cancel exactly.
//
// Round-12 = round-8 dataflow (59.5us) with: separate O-buffer (2 barriers
// per iter, ep2||stage overlap, no dbuf), conflict-free ep1 via permuted
// O column m' = reg*8 + a*4 + lk, ep2 decodes m'->m in its global address
// (LDS addressing identical to round 8; 64B granules still contiguous).
// Keeps: xp reg prefetch, v_cvt_pk bf16, S folded into W, light lgkm-only
// barriers, nt float4 stores, XCD map, grid 512 x NIT 16.

using bf16x8 = __attribute__((ext_vector_type(8))) short;
using f32x4  = __attribute__((ext_vector_type(4))) float;
using f32x2  = __attribute__((ext_vector_type(2))) float;

#define NPT 16                 // n per iteration tile
#define NIT 16                 // iterations per block (256 n per block)
#define PITCH_B 2064           // bytes per n-row (516 dwords), X and O alike
#define BUFB 33024             // 16 rows * 2064
#define LDS_BYTES (2*BUFB)     // Xbuf + Obuf = 66048 -> 2 blocks/CU

// LDS-only barrier: order ds ops across waves without draining the VM queue.
#define BARRIER() asm volatile("s_waitcnt lgkmcnt(0)\n\ts_barrier" ::: "memory")

__device__ inline bf16x8 cvt8v(float4 a, float4 b) {
  union { bf16x8 v; __hip_bfloat162 h[4]; } r;
  r.h[0] = __float22bfloat162_rn(float2{a.x, a.y});
  r.h[1] = __float22bfloat162_rn(float2{a.z, a.w});
  r.h[2] = __float22bfloat162_rn(float2{b.x, b.y});
  r.h[3] = __float22bfloat162_rn(float2{b.z, b.w});
  return r.v;
}

__global__ __launch_bounds__(512, 4)
void crxb_kernel(const float* __restrict__ X, const float* __restrict__ W,
                 float* __restrict__ out) {
  extern __shared__ char smem[];
  char* Xb = smem;               // [n 0..15][r 0..15][j 0..63] bf16, pitch 2064
  char* Ob = smem + BUFB;        // [n 0..15][m' 0..31][r 0..15] f32, pitch 2064

  const int t   = threadIdx.x;
  const int bid = blockIdx.x;
  // XCD-aware mapping: each XCD owns 2 n-groups; all 32 m-tiles of a given
  // n-group land on the same XCD -> X slice stays in that XCD's L2.
  const int ngrp = ((bid & 7) << 1) | ((bid >> 3) & 1);  // 0..15, 256 n each
  const int mt   = bid >> 4;                             // 0..31
  const int c  = mt >> 1;
  const int i0 = (mt & 1) << 5;
  const int m0 = mt << 5;

  const int wid = t >> 6;
  const int l   = t & 63;
  const int lr  = l & 15;            // A row (m within 16) / B col (n)
  const int lk  = l >> 4;            // k-subgroup 0..3
  const int r0w = wid << 1;          // wave owns r0w, r0w+1

  const float S = (float)((0.000333 - 3.33e-07) * (3.3 / 255.0));

  // ---- hoist A fragments: (S*W) fp32 global -> bf16 regs (once per block) ----
  bf16x8 A[2][2][2];                 // [rr][ks][a]
  #pragma unroll
  for (int rr = 0; rr < 2; ++rr)
    #pragma unroll
    for (int ks = 0; ks < 2; ++ks)
      #pragma unroll
      for (int a = 0; a < 2; ++a) {
        const float* gw = W + (((size_t)(c * 16 + r0w + rr) * 64) + (i0 + a * 16 + lr)) * 64
                            + ks * 32 + lk * 8;
        float4 wa = *(const float4*)gw;
        float4 wb = *(const float4*)(gw + 4);
        wa.x *= S; wa.y *= S; wa.z *= S; wa.w *= S;
        wb.x *= S; wb.y *= S; wb.z *= S; wb.w *= S;
        A[rr][ks][a] = cvt8v(wa, wb);
      }

  // ---- prologue: stage X tile 0 into Xb ----
  {
    #pragma unroll
    for (int p = 0; p < 4; ++p) {
      int u = p * 512 + t;                     // 0..2047 bf16x8 units
      int n = u >> 7, r = (u >> 3) & 15, k8 = u & 7;
      const float* gx = X + (((size_t)(ngrp * 256 + n) * 16) + r) * 64 + k8 * 8;
      *(bf16x8*)(Xb + (size_t)n * PITCH_B + r * 128 + k8 * 16) =
          cvt8v(*(const float4*)gx, *(const float4*)(gx + 4));
    }
  }
  BARRIER();

  for (int it = 0; it < NIT; ++it) {
    const int n0 = ngrp * 256 + it * NPT;

    // ---- issue next-tile X loads early (latency hides under compute+ep) ----
    float4 xp[8];
    if (it + 1 < NIT) {
      #pragma unroll
      for (int p = 0; p < 4; ++p) {
        int u = p * 512 + t;
        int n = u >> 7, r = (u >> 3) & 15, k8 = u & 7;
        const float* gx = X + (((size_t)(n0 + NPT + n) * 16) + r) * 64 + k8 * 8;
        xp[2 * p]     = *(const float4*)gx;
        xp[2 * p + 1] = *(const float4*)(gx + 4);
      }
    }

    // ---- compute: 32m x 16n, 2 r's per wave, 8 MFMAs (reads Xb) ----
    f32x4 acc[2][2];                 // [rr][a]
    #pragma unroll
    for (int rr = 0; rr < 2; ++rr)
      #pragma unroll
      for (int a = 0; a < 2; ++a) acc[rr][a] = (f32x4){0.f, 0.f, 0.f, 0.f};

    #pragma unroll
    for (int rr = 0; rr < 2; ++rr) {
      const int r = r0w + rr;
      #pragma unroll
      for (int ks = 0; ks < 2; ++ks) {
        bf16x8 Bf = *(const bf16x8*)(Xb + (size_t)lr * PITCH_B + r * 128 + ks * 64 + lk * 16);
        acc[rr][0] = __builtin_amdgcn_mfma_f32_16x16x32_bf16(A[rr][ks][0], Bf, acc[rr][0], 0, 0, 0);
        acc[rr][1] = __builtin_amdgcn_mfma_f32_16x16x32_bf16(A[rr][ks][1], Bf, acc[rr][1], 0, 0, 0);
      }
    }

    // ---- ep1: acc -> Ob at column m' = reg*8 + a*4 + lk (conflict-free b64:
    //      bank = 4*lr + 16*lk + r0w -> 16 pairs x 4 lanes = 4-phase min) ----
    #pragma unroll
    for (int a = 0; a < 2; ++a)
      #pragma unroll
      for (int reg = 0; reg < 4; ++reg) {
        f32x2 v = {acc[0][a][reg], acc[1][a][reg]};
        const int mp = reg * 8 + a * 4 + lk;      // m' in 0..31
        *(f32x2*)(Ob + ((size_t)lr * 516 + mp * 16 + r0w) * 4) = v;
      }
    BARRIER();   // ep1 visible; all Xb reads done

    // ---- ep2: Ob -> global (decode m'->m); nt stores drain under stage ----
    {
      const int n  = t >> 5;         // 0..15
      const int j0 = t & 31;
      const float* Or = (const float*)(Ob + (size_t)n * PITCH_B);
      float* grow = out + ((size_t)(n0 + n)) * 16384 + (size_t)m0 * 16;
      #pragma unroll
      for (int q = 0; q < 4; ++q) {
        const int jp = q * 32 + j0;               // 0..127 = m'*4 + ri
        const int mp = jp >> 2, ri = jp & 3;
        const int m  = ((mp >> 2) & 1) * 16 + (mp & 3) * 4 + (mp >> 3);  // a*16+lk*4+reg
        f32x4 v = *(const f32x4*)(Or + jp * 4);   // LDS pattern identical to r8
        __builtin_nontemporal_store(v, (f32x4*)(grow + m * 16 + ri * 4));
      }
    }

    // ---- stage next tile into Xb (safe: all Xb reads done at the barrier) ----
    if (it + 1 < NIT) {
      #pragma unroll
      for (int p = 0; p < 4; ++p) {
        int u = p * 512 + t;
        int n = u >> 7, r = (u >> 3) & 15, k8 = u & 7;
        *(bf16x8*)(Xb + (size_t)n * PITCH_B + r * 128 + k8 * 16) = cvt8v(xp[2 * p], xp[2 * p + 1]);
      }
    }
    BARRIER();   // stage visible; ep2's Ob reads done before next ep1
  }
}

extern "C" void kernel_launch(void* const* d_in, const int* in_sizes, int n_in,
                              void* d_out, int out_size, void* d_ws, size_t ws_size,
                              hipStream_t stream) {
  const float* X = (const float*)d_in[0];   // [4096,1,16,64,1]
  const float* W = (const float*)d_in[1];   // [16,16,64,64]
  float* out = (float*)d_out;               // [4096,1024,16]
  (void)in_sizes; (void)n_in; (void)d_ws; (void)ws_size; (void)out_size;

  (void)hipFuncSetAttribute(reinterpret_cast<const void*>(crxb_kernel),
                            hipFuncAttributeMaxDynamicSharedMemorySize, LDS_BYTES);

  crxb_kernel<<<dim3(512), dim3(512), LDS_BYTES, stream>>>(X, W, out);
}

// Round 13
// 59.897 us; speedup vs baseline: 11.7999x; 1.2833x over previous
//
#include <hip/hip_runtime.h>
#include <hip/hip_bf16.h>
#include <stdint.h>

// out[n, m=c*64+i, r] = sum_j (S*W[c,r,i,j]) * X[n,r,j],  S = DELTA_G*DELTA_V
// N=4096, M=1024 (c=16 x i=64), R=16, K=64.  GMIN terms cancel exactly.
//
// Round-13 = round-8 (59.5us) with ONE isolated lever: ep1 bank conflicts.
// O-tile pitch 514 dwords (2056B) instead of sharing X's 516: ep1 f32x2
// bank-pair = (lr + 8*(reg&1) + wid) mod 16 -> 16 distinct per instr =
// 4-phase b64 minimum (was 8 lanes/pair = 2x). ep2 reads two f32x2 (8B
// aligned, conflict-free) and issues the same f32x4 nt global store.
// X staging/compute/barriers byte-identical to round 8.

using bf16x8 = __attribute__((ext_vector_type(8))) short;
using f32x4  = __attribute__((ext_vector_type(4))) float;
using f32x2  = __attribute__((ext_vector_type(2))) float;

#define NPT 16                 // n per iteration tile
#define NIT 16                 // iterations per block (256 n per block)
#define PITCH_B 2064           // X: bytes per n-row (516 dwords), b128-aligned
#define OPITCH_DW 514          // O: dwords per n-row (2056B) -> conflict-free ep1
#define BUFB 33024             // 16 rows * 2064 (O tile 16*2056=32896 fits)
#define LDS_BYTES (2*BUFB)     // 66048: double buffer -> 2 blocks/CU

// LDS-only barrier: order ds ops across waves without draining the VM queue.
#define BARRIER() asm volatile("s_waitcnt lgkmcnt(0)\n\ts_barrier" ::: "memory")

__device__ inline bf16x8 cvt8v(float4 a, float4 b) {
  union { bf16x8 v; __hip_bfloat162 h[4]; } r;
  r.h[0] = __float22bfloat162_rn(float2{a.x, a.y});
  r.h[1] = __float22bfloat162_rn(float2{a.z, a.w});
  r.h[2] = __float22bfloat162_rn(float2{b.x, b.y});
  r.h[3] = __float22bfloat162_rn(float2{b.z, b.w});
  return r.v;
}

__global__ __launch_bounds__(512, 4)
void crxb_kernel(const float* __restrict__ X, const float* __restrict__ W,
                 float* __restrict__ out) {
  extern __shared__ char smem[];
  const int t   = threadIdx.x;
  const int bid = blockIdx.x;
  // XCD-aware mapping: each XCD owns 2 n-groups; all 32 m-tiles of a given
  // n-group land on the same XCD -> X slice stays in that XCD's L2.
  const int ngrp = ((bid & 7) << 1) | ((bid >> 3) & 1);  // 0..15, 256 n each
  const int mt   = bid >> 4;                             // 0..31
  const int c  = mt >> 1;
  const int i0 = (mt & 1) << 5;
  const int m0 = mt << 5;

  const int wid = t >> 6;
  const int l   = t & 63;
  const int lr  = l & 15;            // A row (m within 16) / B col (n)
  const int lk  = l >> 4;            // k-subgroup 0..3
  const int r0w = wid << 1;          // wave owns r0w, r0w+1

  const float S = (float)((0.000333 - 3.33e-07) * (3.3 / 255.0));

  // ---- hoist A fragments: (S*W) fp32 global -> bf16 regs (once per block) ----
  bf16x8 A[2][2][2];                 // [rr][ks][a]
  #pragma unroll
  for (int rr = 0; rr < 2; ++rr)
    #pragma unroll
    for (int ks = 0; ks < 2; ++ks)
      #pragma unroll
      for (int a = 0; a < 2; ++a) {
        const float* gw = W + (((size_t)(c * 16 + r0w + rr) * 64) + (i0 + a * 16 + lr)) * 64
                            + ks * 32 + lk * 8;
        float4 wa = *(const float4*)gw;
        float4 wb = *(const float4*)(gw + 4);
        wa.x *= S; wa.y *= S; wa.z *= S; wa.w *= S;
        wb.x *= S; wb.y *= S; wb.z *= S; wb.w *= S;
        A[rr][ks][a] = cvt8v(wa, wb);
      }

  // ---- prologue: stage X tile 0 into buf0 ----
  {
    #pragma unroll
    for (int p = 0; p < 4; ++p) {
      int u = p * 512 + t;                     // 0..2047 bf16x8 units
      int n = u >> 7, r = (u >> 3) & 15, k8 = u & 7;
      const float* gx = X + (((size_t)(ngrp * 256 + n) * 16) + r) * 64 + k8 * 8;
      *(bf16x8*)(smem + (size_t)n * PITCH_B + r * 128 + k8 * 16) =
          cvt8v(*(const float4*)gx, *(const float4*)(gx + 4));
    }
  }
  BARRIER();

  int cur = 0;
  for (int it = 0; it < NIT; ++it) {
    char* bufc = smem + cur * BUFB;
    char* bufn = smem + (cur ^ 1) * BUFB;
    const int n0 = ngrp * 256 + it * NPT;

    // ---- issue next-tile X loads early (latency hides under compute+eps) ----
    float4 xp[8];
    if (it + 1 < NIT) {
      #pragma unroll
      for (int p = 0; p < 4; ++p) {
        int u = p * 512 + t;
        int n = u >> 7, r = (u >> 3) & 15, k8 = u & 7;
        const float* gx = X + (((size_t)(n0 + NPT + n) * 16) + r) * 64 + k8 * 8;
        xp[2 * p]     = *(const float4*)gx;
        xp[2 * p + 1] = *(const float4*)(gx + 4);
      }
    }

    // ---- compute: 32m x 16n, 2 r's per wave, 8 MFMAs ----
    f32x4 acc[2][2];                 // [rr][a]
    #pragma unroll
    for (int rr = 0; rr < 2; ++rr)
      #pragma unroll
      for (int a = 0; a < 2; ++a) acc[rr][a] = (f32x4){0.f, 0.f, 0.f, 0.f};

    #pragma unroll
    for (int rr = 0; rr < 2; ++rr) {
      const int r = r0w + rr;
      #pragma unroll
      for (int ks = 0; ks < 2; ++ks) {
        bf16x8 Bf = *(const bf16x8*)(bufc + (size_t)lr * PITCH_B + r * 128 + ks * 64 + lk * 16);
        acc[rr][0] = __builtin_amdgcn_mfma_f32_16x16x32_bf16(A[rr][ks][0], Bf, acc[rr][0], 0, 0, 0);
        acc[rr][1] = __builtin_amdgcn_mfma_f32_16x16x32_bf16(A[rr][ks][1], Bf, acc[rr][1], 0, 0, 0);
      }
    }
    BARRIER();                       // all reads of bufc done (LDS order only)

    // ---- ep1: acc -> O (fp32, pitch 514dw) in bufc; conflict-free f32x2 ----
    {
      float* Od = (float*)bufc;
      #pragma unroll
      for (int a = 0; a < 2; ++a)
        #pragma unroll
        for (int reg = 0; reg < 4; ++reg) {
          f32x2 v = {acc[0][a][reg], acc[1][a][reg]};
          const int mm = a * 16 + lk * 4 + reg;   // m within 32
          *(f32x2*)(Od + (size_t)lr * OPITCH_DW + mm * 16 + r0w) = v;
        }
    }
    BARRIER();

    // ---- ep2: O -> global; two b64 LDS reads -> one f32x4 nt store ----
    {
      const int n  = t >> 5;         // 0..15
      const int j0 = t & 31;
      const float* Or = (const float*)bufc + (size_t)n * OPITCH_DW;
      float* gout = out + ((size_t)(n0 + n)) * 16384 + (size_t)m0 * 16;
      #pragma unroll
      for (int q = 0; q < 4; ++q) {
        const int u = (q * 32 + j0) * 4;          // dword offset in row
        f32x2 lo = *(const f32x2*)(Or + u);
        f32x2 hi = *(const f32x2*)(Or + u + 2);
        f32x4 v = {lo[0], lo[1], hi[0], hi[1]};
        __builtin_nontemporal_store(v, (f32x4*)(gout + u));
      }
    }

    // ---- stage next tile: cvt prefetched regs -> bufn ----
    if (it + 1 < NIT) {
      #pragma unroll
      for (int p = 0; p < 4; ++p) {
        int u = p * 512 + t;
        int n = u >> 7, r = (u >> 3) & 15, k8 = u & 7;
        *(bf16x8*)(bufn + (size_t)n * PITCH_B + r * 128 + k8 * 16) = cvt8v(xp[2 * p], xp[2 * p + 1]);
      }
    }
    BARRIER();
    cur ^= 1;
  }
}

extern "C" void kernel_launch(void* const* d_in, const int* in_sizes, int n_in,
                              void* d_out, int out_size, void* d_ws, size_t ws_size,
                              hipStream_t stream) {
  const float* X = (const float*)d_in[0];   // [4096,1,16,64,1]
  const float* W = (const float*)d_in[1];   // [16,16,64,64]
  float* out = (float*)d_out;               // [4096,1024,16]
  (void)in_sizes; (void)n_in; (void)d_ws; (void)ws_size; (void)out_size;

  (void)hipFuncSetAttribute(reinterpret_cast<const void*>(crxb_kernel),
                            hipFuncAttributeMaxDynamicSharedMemorySize, LDS_BYTES);

  crxb_kernel<<<dim3(512), dim3(512), LDS_BYTES, stream>>>(X, W, out);
}